// Round 1
// baseline (80.008 us; speedup 1.0000x reference)
//
#include <hip/hip_runtime.h>
#include <stdint.h>

#define NB 200000
#define BB 4
#define GG 64
#define MAXPOS 128
#define BATCH 256

// ---------------- init: zero counters ----------------
__global__ void rpn_init_kernel(int* counters /* 8 ints + 16 floats = 24 words */) {
    if (threadIdx.x < 24) counters[threadIdx.x] = 0;
}

// ---------------- K1: per-anchor max-IoU/argmax flags ----------------
__global__ __launch_bounds__(256) void rpn_flags_kernel(
        const float* __restrict__ anchors, const float* __restrict__ gt,
        uint8_t* __restrict__ flags, int* __restrict__ posCnt, int* __restrict__ negCnt) {
    int b = blockIdx.y;
    int i = blockIdx.x * 256 + threadIdx.x;
    __shared__ float sG[GG * 4];
    __shared__ float sA2[GG];
    __shared__ int sPos, sNeg;
    if (threadIdx.x < GG * 4) sG[threadIdx.x] = gt[b * GG * 4 + threadIdx.x];
    if (threadIdx.x == 0) { sPos = 0; sNeg = 0; }
    __syncthreads();
    if (threadIdx.x < GG) {
        float x1 = sG[4 * threadIdx.x + 0], y1 = sG[4 * threadIdx.x + 1];
        float x2 = sG[4 * threadIdx.x + 2], y2 = sG[4 * threadIdx.x + 3];
        sA2[threadIdx.x] = (x2 - x1) * (y2 - y1);
    }
    __syncthreads();

    bool p = false, n = false;
    if (i < NB) {
        float4 a = ((const float4*)anchors)[b * NB + i];
        float a1 = (a.z - a.x) * (a.w - a.y);
        float best = -1.0f;
        int bi = 0;
        for (int g = 0; g < GG; ++g) {
            float gx1 = sG[4 * g + 0], gy1 = sG[4 * g + 1];
            float gx2 = sG[4 * g + 2], gy2 = sG[4 * g + 3];
            float ltx = fmaxf(a.x, gx1), lty = fmaxf(a.y, gy1);
            float rbx = fminf(a.z, gx2), rby = fminf(a.w, gy2);
            float w = fmaxf(rbx - ltx, 0.0f), h = fmaxf(rby - lty, 0.0f);
            float inter = w * h;
            float iou = inter / (a1 + sA2[g] - inter);  // ((a1+a2)-inter), same as numpy
            if (iou > best) { best = iou; bi = g; }     // first-max == argmax semantics
        }
        p = (best >= 0.7f);
        n = (best < 0.3f);
        flags[b * NB + i] = (uint8_t)(bi | (p ? 64 : 0) | (n ? 128 : 0));
    }
    unsigned long long mp = __ballot(p), mn = __ballot(n);
    if ((threadIdx.x & 63) == 0) {
        atomicAdd(&sPos, __popcll(mp));
        atomicAdd(&sNeg, __popcll(mn));
    }
    __syncthreads();
    if (threadIdx.x == 0) {
        if (sPos) atomicAdd(&posCnt[b], sPos);
        if (sNeg) atomicAdd(&negCnt[b], sNeg);
    }
}

// ---------------- K2: ordered selection + loss partials ----------------
__global__ __launch_bounds__(1024) void rpn_select_kernel(
        const uint8_t* __restrict__ flags,
        const float* __restrict__ logits, const float* __restrict__ breg,
        const float* __restrict__ anchors, const float* __restrict__ gt,
        const int* __restrict__ posCnt, const int* __restrict__ negCnt,
        float* __restrict__ partial) {
    int b = blockIdx.x;
    const uint8_t* F = flags + b * NB;
    __shared__ int selPos[MAXPOS];
    __shared__ uint8_t selPosG[MAXPOS];
    __shared__ int selNeg[BATCH];
    __shared__ int wP[16], wN[16];
    __shared__ int sBaseP, sBaseN;
    __shared__ float sB, sS;
    int tid = threadIdx.x, lane = tid & 63, wid = tid >> 6;
    int numPos = min(posCnt[b], MAXPOS);
    int numNeg = min(negCnt[b], BATCH - numPos);
    if (tid == 0) { sBaseP = 0; sBaseN = 0; sB = 0.0f; sS = 0.0f; }
    __syncthreads();

    int nChunks = (NB + 1023) / 1024;
    for (int c = 0; c < nChunks; ++c) {
        if (sBaseP >= numPos && sBaseN >= numNeg) break;
        int bp = sBaseP, bn = sBaseN;
        int i = c * 1024 + tid;
        uint8_t f = (i < NB) ? F[i] : (uint8_t)0;
        bool p = (f & 64) != 0, n = (f & 128) != 0;
        unsigned long long mp = __ballot(p), mn = __ballot(n);
        unsigned long long lt = (1ULL << lane) - 1ULL;
        int lpp = __popcll(mp & lt), lpn = __popcll(mn & lt);
        if (lane == 0) { wP[wid] = __popcll(mp); wN[wid] = __popcll(mn); }
        __syncthreads();
        int offP = 0, offN = 0, totP = 0, totN = 0;
        for (int w = 0; w < 16; ++w) {
            int vp = wP[w], vn = wN[w];
            if (w < wid) { offP += vp; offN += vn; }
            totP += vp; totN += vn;
        }
        int rp = bp + offP + lpp;
        int rn = bn + offN + lpn;
        if (p && rp < numPos) { selPos[rp] = i; selPosG[rp] = (uint8_t)(f & 63); }
        if (n && rn < numNeg) { selNeg[rn] = i; }
        __syncthreads();
        if (tid == 0) { sBaseP = bp + totP; sBaseN = bn + totN; }
        __syncthreads();
    }

    // ---- losses over selected samples ----
    float bce_acc = 0.0f, sl1_acc = 0.0f;
    for (int t = tid; t < numPos; t += 1024) {
        int i = selPos[t];
        int g = selPosG[t];
        float x = logits[b * NB + i];
        bce_acc += fmaxf(x, 0.0f) - x + log1pf(expf(-fabsf(x)));
        float4 a = ((const float4*)anchors)[b * NB + i];
        const float* t4 = gt + (size_t)(b * GG + g) * 4;
        float tx1 = t4[0], ty1 = t4[1], tx2 = t4[2], ty2 = t4[3];
        float acx = (a.x + a.z) / 2.0f, acy = (a.y + a.w) / 2.0f;
        float aw = a.z - a.x, ah = a.w - a.y;
        float tcx = (tx1 + tx2) / 2.0f, tcy = (ty1 + ty2) / 2.0f;
        float tw = tx2 - tx1, th = ty2 - ty1;
        float d0 = (tcx - acx) / aw;
        float d1 = (tcy - acy) / ah;
        float d2 = logf(tw / aw);
        float d3 = logf(th / ah);
        float4 r = ((const float4*)breg)[b * NB + i];
        float df;
        df = fabsf(r.x - d0); sl1_acc += (df < 1.0f) ? 0.5f * df * df : df - 0.5f;
        df = fabsf(r.y - d1); sl1_acc += (df < 1.0f) ? 0.5f * df * df : df - 0.5f;
        df = fabsf(r.z - d2); sl1_acc += (df < 1.0f) ? 0.5f * df * df : df - 0.5f;
        df = fabsf(r.w - d3); sl1_acc += (df < 1.0f) ? 0.5f * df * df : df - 0.5f;
    }
    for (int t = tid; t < numNeg; t += 1024) {
        int i = selNeg[t];
        float x = logits[b * NB + i];
        bce_acc += fmaxf(x, 0.0f) + log1pf(expf(-fabsf(x)));
    }
    for (int off = 32; off > 0; off >>= 1) {
        bce_acc += __shfl_down(bce_acc, off);
        sl1_acc += __shfl_down(sl1_acc, off);
    }
    if (lane == 0) {
        atomicAdd(&sB, bce_acc);
        atomicAdd(&sS, sl1_acc);
    }
    __syncthreads();
    if (tid == 0) {
        partial[b * 4 + 0] = sB;
        partial[b * 4 + 1] = (float)(numPos + numNeg);
        partial[b * 4 + 2] = sS;
        partial[b * 4 + 3] = (float)numPos;
    }
}

// ---------------- K3: finalize ----------------
__global__ void rpn_finalize_kernel(const float* __restrict__ partial, float* __restrict__ out) {
    float bce = 0.0f, val = 0.0f, sl1 = 0.0f, np = 0.0f;
    for (int b = 0; b < BB; ++b) {
        bce += partial[b * 4 + 0];
        val += partial[b * 4 + 1];
        sl1 += partial[b * 4 + 2];
        np  += partial[b * 4 + 3];
    }
    out[0] = bce / fmaxf(val, 1.0f);
    out[1] = sl1 / fmaxf(np * 4.0f, 1.0f);
}

extern "C" void kernel_launch(void* const* d_in, const int* in_sizes, int n_in,
                              void* d_out, int out_size, void* d_ws, size_t ws_size,
                              hipStream_t stream) {
    const float* cls  = (const float*)d_in[0];  // [B,N,1]
    const float* breg = (const float*)d_in[1];  // [B,N,4]
    const float* anch = (const float*)d_in[2];  // [B,N,4]
    const float* gt   = (const float*)d_in[3];  // [B,G,4]
    float* out = (float*)d_out;

    uint8_t* flags = (uint8_t*)d_ws;                       // B*N bytes = 800000
    int* posCnt = (int*)((char*)d_ws + 800000);            // [B]
    int* negCnt = posCnt + BB;                             // [B]
    float* partial = (float*)(posCnt + 2 * BB);            // [B*4]

    rpn_init_kernel<<<1, 32, 0, stream>>>(posCnt);
    dim3 g1((NB + 255) / 256, BB);
    rpn_flags_kernel<<<g1, 256, 0, stream>>>(anch, gt, flags, posCnt, negCnt);
    rpn_select_kernel<<<BB, 1024, 0, stream>>>(flags, cls, breg, anch, gt,
                                               posCnt, negCnt, partial);
    rpn_finalize_kernel<<<1, 1, 0, stream>>>(partial, out);
}

// Round 2
// 46.799 us; speedup vs baseline: 1.7096x; 1.7096x over previous
//
#include <hip/hip_runtime.h>
#include <stdint.h>

#define NB 200000
#define BB 4
#define GG 64
#define MAXPOS 128
#define BATCH 256
#define CH 256
#define NCH ((NB + CH - 1) / CH)   // 782

// ---------------- K0: expand gt to (x1,y1,x2,y2,area,pad,pad,pad) ----------------
__global__ void rpn_prep_kernel(const float* __restrict__ gt, float* __restrict__ gtx) {
    int t = blockIdx.x * blockDim.x + threadIdx.x;
    if (t < BB * GG) {
        float4 g4 = ((const float4*)gt)[t];
        float* o = gtx + t * 8;
        o[0] = g4.x; o[1] = g4.y; o[2] = g4.z; o[3] = g4.w;
        o[4] = (g4.z - g4.x) * (g4.w - g4.y);
        o[5] = 0.0f; o[6] = 0.0f; o[7] = 0.0f;
    }
}

// ---------------- K1: per-anchor argmax-IoU flags + per-chunk counts ----------------
__global__ __launch_bounds__(256) void rpn_flags_kernel(
        const float* __restrict__ anchors, const float* __restrict__ gtx,
        uint8_t* __restrict__ flags, uint32_t* __restrict__ chunkCnt) {
    int b = blockIdx.y;
    int i = blockIdx.x * CH + threadIdx.x;
    const float* __restrict__ G = gtx + b * GG * 8;   // uniform -> s_load
    __shared__ int wCnt[4];
    bool p = false, n = false;
    if (i < NB) {
        float4 a = ((const float4*)anchors)[(size_t)b * NB + i];
        float a1 = (a.z - a.x) * (a.w - a.y);
        float ib = -1.0f, ub = 1.0f;   // best inter / best union (iou = ib/ub)
        int bi = 0;
        #pragma unroll
        for (int g = 0; g < GG; ++g) {
            float gx1 = G[g * 8 + 0], gy1 = G[g * 8 + 1];
            float gx2 = G[g * 8 + 2], gy2 = G[g * 8 + 3];
            float ga  = G[g * 8 + 4];
            float w = fminf(a.z, gx2) - fmaxf(a.x, gx1);
            float h = fminf(a.w, gy2) - fmaxf(a.y, gy1);
            w = fmaxf(w, 0.0f); h = fmaxf(h, 0.0f);
            float inter = w * h;
            float u = (a1 + ga) - inter;          // union > 0 always (valid boxes)
            bool better = inter * ub > ib * u;    // iou_g > best  (cross-mult)
            ib = better ? inter : ib;
            ub = better ? u : ub;
            bi = better ? g : bi;
        }
        float best = ib / ub;                     // single exact div for thresholds
        p = best >= 0.7f;
        n = best < 0.3f;
        flags[(size_t)b * NB + i] = (uint8_t)(bi | (p ? 64 : 0) | (n ? 128 : 0));
    }
    unsigned long long mp = __ballot(p), mn = __ballot(n);
    int wid = threadIdx.x >> 6;
    if ((threadIdx.x & 63) == 0)
        wCnt[wid] = __popcll(mp) | (__popcll(mn) << 16);
    __syncthreads();
    if (threadIdx.x == 0) {
        int s = wCnt[0] + wCnt[1] + wCnt[2] + wCnt[3];   // pos in low16, neg in high16
        chunkCnt[b * NCH + blockIdx.x] = (uint32_t)s;
    }
}

// ---------------- K2: scan chunk counts, parallel ordered selection, loss ----------------
__global__ __launch_bounds__(1024) void rpn_select_kernel(
        const uint8_t* __restrict__ flags,
        const float* __restrict__ logits, const float* __restrict__ breg,
        const float* __restrict__ anchors, const float* __restrict__ gt,
        const uint32_t* __restrict__ chunkCnt,
        float* __restrict__ partial) {
    int b = blockIdx.x;
    const uint8_t* __restrict__ F = flags + (size_t)b * NB;
    __shared__ int basP[NCH], basN[NCH];
    __shared__ unsigned long long wTot[16];
    __shared__ int sNumPos, sNumNeg;
    __shared__ int selPos[MAXPOS];
    __shared__ uint8_t selPosG[MAXPOS];
    __shared__ int selNeg[BATCH];
    __shared__ float sB, sS;
    int tid = threadIdx.x, lane = tid & 63, wid = tid >> 6;

    // --- block-wide exclusive scan of packed (pos, neg) chunk counts ---
    unsigned long long e = 0ULL;
    if (tid < NCH) {
        uint32_t c = chunkCnt[b * NCH + tid];
        e = (unsigned long long)(c & 0xFFFFu) | ((unsigned long long)(c >> 16) << 32);
    }
    unsigned long long inc = e;
    for (int off = 1; off < 64; off <<= 1) {
        unsigned long long v = __shfl_up(inc, off);
        if (lane >= off) inc += v;
    }
    if (lane == 63) wTot[wid] = inc;
    if (tid == 0) { sB = 0.0f; sS = 0.0f; }
    __syncthreads();
    if (wid == 0) {
        unsigned long long w = (lane < 16) ? wTot[lane] : 0ULL;
        unsigned long long winc = w;
        for (int off = 1; off < 16; off <<= 1) {
            unsigned long long v = __shfl_up(winc, off);
            if (lane >= off) winc += v;
        }
        if (lane < 16) wTot[lane] = winc - w;     // exclusive base per wave
        if (lane == 15) {
            int tp = (int)(winc & 0xFFFFFFFFULL);
            int tn = (int)(winc >> 32);
            int np_ = min(tp, MAXPOS);
            sNumPos = np_;
            sNumNeg = min(tn, BATCH - np_);
        }
    }
    __syncthreads();
    if (tid < NCH) {
        unsigned long long ex = wTot[wid] + (inc - e);
        basP[tid] = (int)(ex & 0xFFFFFFFFULL);
        basN[tid] = (int)(ex >> 32);
    }
    __syncthreads();
    int numPos = sNumPos, numNeg = sNumNeg;

    // --- parallel ordered selection: wave w handles chunks w, w+16, ... ---
    for (int c = wid; c < NCH; c += 16) {
        int bp = basP[c], bn = basN[c];
        if (bp >= numPos && bn >= numNeg) break;  // monotone bases, wave-uniform
        int offP = 0, offN = 0;
        #pragma unroll
        for (int s = 0; s < 4; ++s) {
            int idx = c * CH + s * 64 + lane;
            uint8_t f = (idx < NB) ? F[idx] : (uint8_t)0;
            bool p = (f & 64) != 0, n = (f & 128) != 0;
            unsigned long long mp = __ballot(p), mn = __ballot(n);
            unsigned long long lt = (1ULL << lane) - 1ULL;
            int rp = bp + offP + __popcll(mp & lt);
            int rn = bn + offN + __popcll(mn & lt);
            if (p && rp < numPos) { selPos[rp] = idx; selPosG[rp] = (uint8_t)(f & 63); }
            if (n && rn < numNeg) { selNeg[rn] = idx; }
            offP += __popcll(mp); offN += __popcll(mn);
        }
    }
    __syncthreads();

    // --- losses over selected samples ---
    float bce_acc = 0.0f, sl1_acc = 0.0f;
    for (int t = tid; t < numPos; t += 1024) {
        int i = selPos[t];
        int g = selPosG[t];
        float x = logits[(size_t)b * NB + i];
        bce_acc += fmaxf(x, 0.0f) - x + log1pf(expf(-fabsf(x)));
        float4 a = ((const float4*)anchors)[(size_t)b * NB + i];
        const float* t4 = gt + (size_t)(b * GG + g) * 4;
        float tx1 = t4[0], ty1 = t4[1], tx2 = t4[2], ty2 = t4[3];
        float acx = (a.x + a.z) / 2.0f, acy = (a.y + a.w) / 2.0f;
        float aw = a.z - a.x, ah = a.w - a.y;
        float tcx = (tx1 + tx2) / 2.0f, tcy = (ty1 + ty2) / 2.0f;
        float tw = tx2 - tx1, th = ty2 - ty1;
        float d0 = (tcx - acx) / aw;
        float d1 = (tcy - acy) / ah;
        float d2 = logf(tw / aw);
        float d3 = logf(th / ah);
        float4 r = ((const float4*)breg)[(size_t)b * NB + i];
        float df;
        df = fabsf(r.x - d0); sl1_acc += (df < 1.0f) ? 0.5f * df * df : df - 0.5f;
        df = fabsf(r.y - d1); sl1_acc += (df < 1.0f) ? 0.5f * df * df : df - 0.5f;
        df = fabsf(r.z - d2); sl1_acc += (df < 1.0f) ? 0.5f * df * df : df - 0.5f;
        df = fabsf(r.w - d3); sl1_acc += (df < 1.0f) ? 0.5f * df * df : df - 0.5f;
    }
    for (int t = tid; t < numNeg; t += 1024) {
        int i = selNeg[t];
        float x = logits[(size_t)b * NB + i];
        bce_acc += fmaxf(x, 0.0f) + log1pf(expf(-fabsf(x)));
    }
    for (int off = 32; off > 0; off >>= 1) {
        bce_acc += __shfl_down(bce_acc, off);
        sl1_acc += __shfl_down(sl1_acc, off);
    }
    if (lane == 0) {
        atomicAdd(&sB, bce_acc);
        atomicAdd(&sS, sl1_acc);
    }
    __syncthreads();
    if (tid == 0) {
        partial[b * 4 + 0] = sB;
        partial[b * 4 + 1] = (float)(numPos + numNeg);
        partial[b * 4 + 2] = sS;
        partial[b * 4 + 3] = (float)numPos;
    }
}

// ---------------- K3: finalize ----------------
__global__ void rpn_finalize_kernel(const float* __restrict__ partial, float* __restrict__ out) {
    float bce = 0.0f, val = 0.0f, sl1 = 0.0f, np = 0.0f;
    for (int b = 0; b < BB; ++b) {
        bce += partial[b * 4 + 0];
        val += partial[b * 4 + 1];
        sl1 += partial[b * 4 + 2];
        np  += partial[b * 4 + 3];
    }
    out[0] = bce / fmaxf(val, 1.0f);
    out[1] = sl1 / fmaxf(np * 4.0f, 1.0f);
}

extern "C" void kernel_launch(void* const* d_in, const int* in_sizes, int n_in,
                              void* d_out, int out_size, void* d_ws, size_t ws_size,
                              hipStream_t stream) {
    const float* cls  = (const float*)d_in[0];  // [B,N,1]
    const float* breg = (const float*)d_in[1];  // [B,N,4]
    const float* anch = (const float*)d_in[2];  // [B,N,4]
    const float* gt   = (const float*)d_in[3];  // [B,G,4]
    float* out = (float*)d_out;

    float*    gtx      = (float*)d_ws;                              // 2048 floats (8KB)
    uint8_t*  flags    = (uint8_t*)d_ws + 8192;                     // B*N bytes
    uint32_t* chunkCnt = (uint32_t*)((uint8_t*)d_ws + 8192 + 800000);  // B*NCH
    float*    partial  = (float*)((uint8_t*)d_ws + 8192 + 800000 + BB * NCH * 4);

    rpn_prep_kernel<<<1, 256, 0, stream>>>(gt, gtx);
    dim3 g1(NCH, BB);
    rpn_flags_kernel<<<g1, 256, 0, stream>>>(anch, gtx, flags, chunkCnt);
    rpn_select_kernel<<<BB, 1024, 0, stream>>>(flags, cls, breg, anch, gt,
                                               chunkCnt, partial);
    rpn_finalize_kernel<<<1, 1, 0, stream>>>(partial, out);
}